// Round 1
// baseline (780.049 us; speedup 1.0000x reference)
//
#include <hip/hip_runtime.h>

#define NN 65536
#define NE 1048576
#define NODE_F 32
#define EDGE_F 8
#define HID 64
#define NBATCH 64

// ---------------- support = x @ W   (x:[N,K], W:[K,64]) ----------------
template<int K>
__global__ __launch_bounds__(256) void node_linear(const float* __restrict__ x,
                                                   const float* __restrict__ W,
                                                   float* __restrict__ out, int n_nodes) {
    const int lane = threadIdx.x & 63;
    const int wv = threadIdx.x >> 6;
    float wr[K];
#pragma unroll
    for (int k = 0; k < K; ++k) wr[k] = W[k * HID + lane];
    int wid = blockIdx.x * 4 + wv;
    const int nw = gridDim.x * 4;
    for (int n0 = wid; n0 < n_nodes; n0 += nw) {
        const int n = __builtin_amdgcn_readfirstlane(n0);
        const float* xr = x + (size_t)n * K;
        float acc = 0.f;
#pragma unroll
        for (int k = 0; k < K; ++k) acc = fmaf(xr[k], wr[k], acc);
        out[(size_t)n * HID + lane] = acc;
    }
}

// ---------------- fused edge-MLP + gather + gated scatter ----------------
// enc = relu(ef @ W1 + b1) @ W2 + b2 ; msg = support[src]*enc ; atomic agg[tgt] += msg
__global__ __launch_bounds__(256) void edge_conv(
    const float* __restrict__ ef, const int* __restrict__ Esrc, const int* __restrict__ Etgt,
    const float* __restrict__ support,
    const float* __restrict__ W1, const float* __restrict__ b1,
    const float* __restrict__ W2, const float* __restrict__ b2,
    float* __restrict__ agg)
{
    __shared__ float h_lds[4][64];
    const int lane = threadIdx.x & 63;
    const int wv = threadIdx.x >> 6;
    float w1r[EDGE_F];
#pragma unroll
    for (int k = 0; k < EDGE_F; ++k) w1r[k] = W1[k * HID + lane];
    float w2r[HID];
#pragma unroll
    for (int k = 0; k < HID; ++k) w2r[k] = W2[k * HID + lane];
    const float b1v = b1[lane];
    const float b2v = b2[lane];

    int wid = blockIdx.x * 4 + wv;
    const int nw = gridDim.x * 4;
    for (int e0 = wid; e0 < NE; e0 += nw) {
        const int e = __builtin_amdgcn_readfirstlane(e0);
        const int src = Esrc[e];
        const int tgt = Etgt[e];
        const float* efr = ef + (size_t)e * EDGE_F;
        float h = b1v;
#pragma unroll
        for (int k = 0; k < EDGE_F; ++k) h = fmaf(efr[k], w1r[k], h);
        h_lds[wv][lane] = fmaxf(h, 0.f);
        float acc = b2v;
#pragma unroll
        for (int k = 0; k < HID; k += 4) {
            const float4 hv = *(const float4*)(&h_lds[wv][k]);
            acc = fmaf(hv.x, w2r[k + 0], acc);
            acc = fmaf(hv.y, w2r[k + 1], acc);
            acc = fmaf(hv.z, w2r[k + 2], acc);
            acc = fmaf(hv.w, w2r[k + 3], acc);
        }
        const float sv = support[(size_t)src * HID + lane];
        atomicAdd(&agg[(size_t)tgt * HID + lane], sv * acc);
    }
}

// ---------------- x = relu(x + b[feat]) over [N,64], float4 ----------------
__global__ __launch_bounds__(256) void bias_relu(float* __restrict__ x, const float* __restrict__ b, int n4) {
    int i = blockIdx.x * 256 + threadIdx.x;
    const int stride = gridDim.x * 256;
    for (; i < n4; i += stride) {
        float4 v = ((float4*)x)[i];
        const int f = (i & 15) * 4;
        v.x = fmaxf(v.x + b[f + 0], 0.f);
        v.y = fmaxf(v.y + b[f + 1], 0.f);
        v.z = fmaxf(v.z + b[f + 2], 0.f);
        v.w = fmaxf(v.w + b[f + 3], 0.f);
        ((float4*)x)[i] = v;
    }
}

// ---------------- support3[n] = x[n,:] . w  (w:[64]) ----------------
__global__ __launch_bounds__(256) void node_dot(const float* __restrict__ x, const float* __restrict__ w,
                                                float* __restrict__ out, int n_nodes) {
    const int lane = threadIdx.x & 63;
    const int wv = threadIdx.x >> 6;
    const float wk = w[lane];
    int wid = blockIdx.x * 4 + wv;
    const int nw = gridDim.x * 4;
    for (int n = wid; n < n_nodes; n += nw) {
        float v = x[(size_t)n * HID + lane] * wk;
#pragma unroll
        for (int off = 32; off >= 1; off >>= 1) v += __shfl_xor(v, off, 64);
        if (lane == 0) out[n] = v;
    }
}

// ---------------- layer-3 edge pass (scalar features) ----------------
__global__ __launch_bounds__(256) void edge_conv_out(
    const float* __restrict__ ef, const int* __restrict__ Esrc, const int* __restrict__ Etgt,
    const float* __restrict__ support,      // [N]
    const float* __restrict__ W1, const float* __restrict__ b1,   // [8],[1]
    const float* __restrict__ W2, const float* __restrict__ b2,   // [1],[1]
    float* __restrict__ agg)                 // [N]
{
    int e = blockIdx.x * 256 + threadIdx.x;
    const int stride = gridDim.x * 256;
    float w[8];
#pragma unroll
    for (int k = 0; k < 8; ++k) w[k] = W1[k];
    const float b1v = b1[0], w2 = W2[0], b2v = b2[0];
    for (; e < NE; e += stride) {
        const float4 a = *(const float4*)(ef + (size_t)e * 8);
        const float4 c = *(const float4*)(ef + (size_t)e * 8 + 4);
        float h = b1v;
        h = fmaf(a.x, w[0], h); h = fmaf(a.y, w[1], h);
        h = fmaf(a.z, w[2], h); h = fmaf(a.w, w[3], h);
        h = fmaf(c.x, w[4], h); h = fmaf(c.y, w[5], h);
        h = fmaf(c.z, w[6], h); h = fmaf(c.w, w[7], h);
        const float enc = fmaxf(h, 0.f) * w2 + b2v;
        const float msg = support[Esrc[e]] * enc;
        atomicAdd(&agg[Etgt[e]], msg);
    }
}

// ---------------- batch sum-pool: out[batch[n]] += agg[n] + b_out ----------------
__global__ __launch_bounds__(256) void pool(const float* __restrict__ agg, const int* __restrict__ batch,
                                            const float* __restrict__ b_out, float* __restrict__ out) {
    const int n = blockIdx.x * 256 + threadIdx.x;
    const int lane = threadIdx.x & 63;
    float v = agg[n] + b_out[0];
    const int b = batch[n];
    const int b0 = __shfl(b, 0, 64);
    if (__all(b == b0)) {
#pragma unroll
        for (int off = 32; off >= 1; off >>= 1) v += __shfl_xor(v, off, 64);
        if (lane == 0) atomicAdd(&out[b0], v);
    } else {
        atomicAdd(&out[b], v);
    }
}

extern "C" void kernel_launch(void* const* d_in, const int* in_sizes, int n_in,
                              void* d_out, int out_size, void* d_ws, size_t ws_size,
                              hipStream_t stream) {
    const float* nf    = (const float*)d_in[0];
    const float* ef    = (const float*)d_in[1];
    const int*   Esrc  = (const int*)d_in[2];
    const int*   Etgt  = (const int*)d_in[3];
    const int*   batch = (const int*)d_in[4];
    const float* W_in  = (const float*)d_in[5];
    const float* b_in  = (const float*)d_in[6];
    const float* W_mid = (const float*)d_in[7];
    const float* b_mid = (const float*)d_in[8];
    const float* W_out = (const float*)d_in[9];
    const float* b_out = (const float*)d_in[10];
    const float* eiW1  = (const float*)d_in[11];
    const float* eib1  = (const float*)d_in[12];
    const float* eiW2  = (const float*)d_in[13];
    const float* eib2  = (const float*)d_in[14];
    const float* emW1  = (const float*)d_in[15];
    const float* emb1  = (const float*)d_in[16];
    const float* emW2  = (const float*)d_in[17];
    const float* emb2  = (const float*)d_in[18];
    const float* eoW1  = (const float*)d_in[19];
    const float* eob1  = (const float*)d_in[20];
    const float* eoW2  = (const float*)d_in[21];
    const float* eob2  = (const float*)d_in[22];

    float* bufA = (float*)d_ws;                          // support  [N,64] 16MB
    float* bufB = bufA + (size_t)NN * HID;               // agg / x  [N,64] 16MB
    float* sup3 = bufB + (size_t)NN * HID;               // [N] 256KB
    float* agg3 = sup3 + NN;                             // [N] 256KB

    hipMemsetAsync(d_out, 0, NBATCH * sizeof(float), stream);
    hipMemsetAsync(bufB, 0, (size_t)NN * HID * sizeof(float), stream);

    // layer 1
    node_linear<NODE_F><<<1024, 256, 0, stream>>>(nf, W_in, bufA, NN);
    edge_conv<<<2048, 256, 0, stream>>>(ef, Esrc, Etgt, bufA, eiW1, eib1, eiW2, eib2, bufB);
    bias_relu<<<1024, 256, 0, stream>>>(bufB, b_in, NN * HID / 4);

    // layer 2
    node_linear<HID><<<1024, 256, 0, stream>>>(bufB, W_mid, bufA, NN);
    hipMemsetAsync(bufB, 0, (size_t)NN * HID * sizeof(float), stream);
    edge_conv<<<2048, 256, 0, stream>>>(ef, Esrc, Etgt, bufA, emW1, emb1, emW2, emb2, bufB);
    bias_relu<<<1024, 256, 0, stream>>>(bufB, b_mid, NN * HID / 4);

    // layer 3 (OUT_F = 1)
    node_dot<<<256, 256, 0, stream>>>(bufB, W_out, sup3, NN);
    hipMemsetAsync(agg3, 0, NN * sizeof(float), stream);
    edge_conv_out<<<1024, 256, 0, stream>>>(ef, Esrc, Etgt, sup3, eoW1, eob1, eoW2, eob2, agg3);

    // pooling
    pool<<<NN / 256, 256, 0, stream>>>(agg3, batch, b_out, (float*)d_out);
}